// Round 1
// baseline (1643.121 us; speedup 1.0000x reference)
//
#include <hip/hip_runtime.h>
#include <math.h>

#define N_NODES    100000
#define N_EDGES    1600000
#define NUM_GRAPHS 512
#define D1 3
#define D2 50
#define D3 15
#define D5 10
#define NCLS 6
#define BN_EPS 1e-5f

// LDS layout (floats), rows padded to multiple of 4 for aligned b128 reads
#define OFF_EW1 0       // [9][52]
#define OFF_EW2 468     // [50][16]
#define OFF_NW1 1268    // [18][52]
#define OFF_NW2 2204    // [50][16]
#define OFF_EB1 3004    // [50]
#define OFF_EB2 3054    // [15]
#define OFF_NB1 3069    // [50]
#define OFF_NB2 3119    // [15]
#define LDS_FLOATS 3134

__global__ __launch_bounds__(256) void edge_kernel(
    const float* __restrict__ x, const float* __restrict__ edge_attr,
    const float* __restrict__ ew1, const float* __restrict__ eb1,
    const float* __restrict__ ew2, const float* __restrict__ eb2,
    const float* __restrict__ nw1, const float* __restrict__ nb1,
    const float* __restrict__ nw2, const float* __restrict__ nb2,
    const int* __restrict__ edge_index,
    float* __restrict__ x2sum)   // [N_NODES][16], slot 15 = count
{
    __shared__ float s[LDS_FLOATS];
    // zero (pads), then fill
    for (int i = threadIdx.x; i < LDS_FLOATS; i += 256) s[i] = 0.0f;
    __syncthreads();
    for (int t = threadIdx.x; t < 9 * 50; t += 256) {
        int i = t / 50, j = t - i * 50;
        s[OFF_EW1 + i * 52 + j] = ew1[t];
    }
    for (int t = threadIdx.x; t < 50 * 15; t += 256) {
        int j = t / 15, k = t - j * 15;
        s[OFF_EW2 + j * 16 + k] = ew2[t];
    }
    for (int t = threadIdx.x; t < 18 * 50; t += 256) {
        int i = t / 50, j = t - i * 50;
        s[OFF_NW1 + i * 52 + j] = nw1[t];
    }
    for (int t = threadIdx.x; t < 50 * 15; t += 256) {
        int j = t / 15, k = t - j * 15;
        s[OFF_NW2 + j * 16 + k] = nw2[t];
    }
    for (int t = threadIdx.x; t < 50; t += 256) s[OFF_EB1 + t] = eb1[t];
    for (int t = threadIdx.x; t < 15; t += 256) s[OFF_EB2 + t] = eb2[t];
    for (int t = threadIdx.x; t < 50; t += 256) s[OFF_NB1 + t] = nb1[t];
    for (int t = threadIdx.x; t < 15; t += 256) s[OFF_NB2 + t] = nb2[t];
    __syncthreads();

    int e = blockIdx.x * 256 + threadIdx.x;
    if (e >= N_EDGES) return;

    int row = edge_index[e];
    int col = edge_index[N_EDGES + e];

    float ein[9];
    ein[0] = x[row * 3 + 0]; ein[1] = x[row * 3 + 1]; ein[2] = x[row * 3 + 2];
    ein[3] = x[col * 3 + 0]; ein[4] = x[col * 3 + 1]; ein[5] = x[col * 3 + 2];
    ein[6] = edge_attr[e * 3 + 0];
    ein[7] = edge_attr[e * 3 + 1];
    ein[8] = edge_attr[e * 3 + 2];

    // edge MLP layer 1: [9] -> [50], relu
    float h1[D2];
    #pragma unroll
    for (int j = 0; j < D2; j++) h1[j] = s[OFF_EB1 + j];
    #pragma unroll
    for (int i = 0; i < 9; i++) {
        float v = ein[i];
        #pragma unroll
        for (int j = 0; j < D2; j++)
            h1[j] = fmaf(v, s[OFF_EW1 + i * 52 + j], h1[j]);
    }
    #pragma unroll
    for (int j = 0; j < D2; j++) h1[j] = fmaxf(h1[j], 0.0f);

    // edge MLP layer 2: [50] -> [15]
    float e2[D3];
    #pragma unroll
    for (int k = 0; k < D3; k++) e2[k] = s[OFF_EB2 + k];
    #pragma unroll
    for (int j = 0; j < D2; j++) {
        float v = h1[j];
        #pragma unroll
        for (int k = 0; k < D3; k++)
            e2[k] = fmaf(v, s[OFF_EW2 + j * 16 + k], e2[k]);
    }

    // node MLP layer 1: [x[col](3), e2(15)] -> [50], relu
    float h2[D2];
    #pragma unroll
    for (int j = 0; j < D2; j++) h2[j] = s[OFF_NB1 + j];
    #pragma unroll
    for (int i = 0; i < 3; i++) {
        float v = ein[3 + i];
        #pragma unroll
        for (int j = 0; j < D2; j++)
            h2[j] = fmaf(v, s[OFF_NW1 + i * 52 + j], h2[j]);
    }
    #pragma unroll
    for (int k = 0; k < D3; k++) {
        float v = e2[k];
        #pragma unroll
        for (int j = 0; j < D2; j++)
            h2[j] = fmaf(v, s[OFF_NW1 + (3 + k) * 52 + j], h2[j]);
    }
    #pragma unroll
    for (int j = 0; j < D2; j++) h2[j] = fmaxf(h2[j], 0.0f);

    // node MLP layer 2: [50] -> [15]
    float msg[D3];
    #pragma unroll
    for (int k = 0; k < D3; k++) msg[k] = s[OFF_NB2 + k];
    #pragma unroll
    for (int j = 0; j < D2; j++) {
        float v = h2[j];
        #pragma unroll
        for (int k = 0; k < D3; k++)
            msg[k] = fmaf(v, s[OFF_NW2 + j * 16 + k], msg[k]);
    }

    // scatter-add into per-node accumulator (slot 15 = edge count)
    float* dst = x2sum + (size_t)row * 16;
    #pragma unroll
    for (int k = 0; k < D3; k++) atomicAdd(&dst[k], msg[k]);
    atomicAdd(&dst[15], 1.0f);
}

__global__ __launch_bounds__(256) void node_kernel(
    const float* __restrict__ x2sum, const int* __restrict__ batch,
    float* __restrict__ gsum)   // [NUM_GRAPHS][16], slot 15 = node count
{
    int n = blockIdx.x * 256 + threadIdx.x;
    if (n >= N_NODES) return;
    const float* src = x2sum + (size_t)n * 16;
    float c = src[15];
    float inv = 1.0f / fmaxf(c, 1.0f);
    int g = batch[n];
    float* dst = gsum + (size_t)g * 16;
    #pragma unroll
    for (int k = 0; k < D3; k++) atomicAdd(&dst[k], src[k] * inv);
    atomicAdd(&dst[15], 1.0f);
}

__global__ __launch_bounds__(512) void head_kernel(
    const float* __restrict__ gsum,
    const float* __restrict__ fc1w, const float* __restrict__ fc1b,
    const float* __restrict__ gamma, const float* __restrict__ beta,
    const float* __restrict__ fc2w, const float* __restrict__ fc2b,
    float* __restrict__ out)
{
    __shared__ float ssum[D5], ssq[D5], smu[D5], sistd[D5];
    int g = threadIdx.x;       // one graph per thread, 512 threads
    if (g < D5) { ssum[g] = 0.0f; ssq[g] = 0.0f; }
    __syncthreads();

    const float* src = gsum + (size_t)g * 16;
    float inv = 1.0f / fmaxf(src[15], 1.0f);
    float u[D3];
    #pragma unroll
    for (int k = 0; k < D3; k++) u[k] = src[k] * inv;

    float h[D5];
    #pragma unroll
    for (int c = 0; c < D5; c++) h[c] = fc1b[c];
    #pragma unroll
    for (int k = 0; k < D3; k++) {
        float v = u[k];
        #pragma unroll
        for (int c = 0; c < D5; c++) h[c] = fmaf(v, fc1w[k * D5 + c], h[c]);
    }

    // BN stats over the 512 graphs: wave shuffle-reduce then shared atomics
    int lane = threadIdx.x & 63;
    #pragma unroll
    for (int c = 0; c < D5; c++) {
        float v = h[c];
        float v2 = v * v;
        #pragma unroll
        for (int off = 32; off >= 1; off >>= 1) {
            v  += __shfl_xor(v,  off);
            v2 += __shfl_xor(v2, off);
        }
        if (lane == 0) { atomicAdd(&ssum[c], v); atomicAdd(&ssq[c], v2); }
    }
    __syncthreads();
    if (g < D5) {
        float mu = ssum[g] * (1.0f / NUM_GRAPHS);
        float var = ssq[g] * (1.0f / NUM_GRAPHS) - mu * mu;
        smu[g] = mu;
        sistd[g] = rsqrtf(var + BN_EPS);
    }
    __syncthreads();

    float hn[D5];
    #pragma unroll
    for (int c = 0; c < D5; c++) {
        float v = gamma[c] * (h[c] - smu[c]) * sistd[c] + beta[c];
        hn[c] = fmaxf(v, 0.0f);
    }

    float lg[NCLS];
    #pragma unroll
    for (int j = 0; j < NCLS; j++) lg[j] = fc2b[j];
    #pragma unroll
    for (int c = 0; c < D5; c++) {
        float v = hn[c];
        #pragma unroll
        for (int j = 0; j < NCLS; j++) lg[j] = fmaf(v, fc2w[c * NCLS + j], lg[j]);
    }

    float m = lg[0];
    #pragma unroll
    for (int j = 1; j < NCLS; j++) m = fmaxf(m, lg[j]);
    float se = 0.0f;
    #pragma unroll
    for (int j = 0; j < NCLS; j++) se += expf(lg[j] - m);
    float lse = logf(se);
    #pragma unroll
    for (int j = 0; j < NCLS; j++) out[g * NCLS + j] = lg[j] - m - lse;
}

extern "C" void kernel_launch(void* const* d_in, const int* in_sizes, int n_in,
                              void* d_out, int out_size, void* d_ws, size_t ws_size,
                              hipStream_t stream) {
    const float* x         = (const float*)d_in[0];
    const float* edge_attr = (const float*)d_in[1];
    const float* ew1  = (const float*)d_in[2];
    const float* eb1  = (const float*)d_in[3];
    const float* ew2  = (const float*)d_in[4];
    const float* eb2  = (const float*)d_in[5];
    const float* nw1  = (const float*)d_in[6];
    const float* nb1  = (const float*)d_in[7];
    const float* nw2  = (const float*)d_in[8];
    const float* nb2  = (const float*)d_in[9];
    const float* fc1w = (const float*)d_in[10];
    const float* fc1b = (const float*)d_in[11];
    const float* gamma= (const float*)d_in[12];
    const float* beta = (const float*)d_in[13];
    const float* fc2w = (const float*)d_in[14];
    const float* fc2b = (const float*)d_in[15];
    const int* edge_index = (const int*)d_in[16];
    const int* batch      = (const int*)d_in[17];

    float* x2sum = (float*)d_ws;                       // N_NODES*16
    float* gsum  = x2sum + (size_t)N_NODES * 16;       // NUM_GRAPHS*16
    size_t zbytes = ((size_t)N_NODES * 16 + (size_t)NUM_GRAPHS * 16) * sizeof(float);
    hipMemsetAsync(d_ws, 0, zbytes, stream);

    edge_kernel<<<(N_EDGES + 255) / 256, 256, 0, stream>>>(
        x, edge_attr, ew1, eb1, ew2, eb2, nw1, nb1, nw2, nb2,
        edge_index, x2sum);
    node_kernel<<<(N_NODES + 255) / 256, 256, 0, stream>>>(
        x2sum, batch, gsum);
    head_kernel<<<1, 512, 0, stream>>>(
        gsum, fc1w, fc1b, gamma, beta, fc2w, fc2b, (float*)d_out);
}

// Round 2
// 613.135 us; speedup vs baseline: 2.6799x; 2.6799x over previous
//
#include <hip/hip_runtime.h>
#include <math.h>

#define N_NODES    100000
#define N_EDGES    1600000
#define NUM_GRAPHS 512
#define D1 3
#define D2 50
#define D3 15
#define D5 10
#define NCLS 6
#define BN_EPS 1e-5f

// LDS layout (floats), rows padded for aligned vector reads
#define OFF_EW1 0       // [9][52]
#define OFF_EW2 468     // [50][16]
#define OFF_NW1 1268    // [18][52]
#define OFF_NW2 2204    // [50][16]
#define OFF_EB1 3004    // [50]
#define OFF_EB2 3054    // [15]
#define OFF_NB1 3069    // [50]
#define OFF_NB2 3119    // [15]
#define LDS_FLOATS 3134

#define NBLK1 ((N_NODES + 1023) / 1024)   // 98 scan blocks

__device__ __forceinline__ void stage_weights(float* s,
    const float* __restrict__ ew1, const float* __restrict__ eb1,
    const float* __restrict__ ew2, const float* __restrict__ eb2,
    const float* __restrict__ nw1, const float* __restrict__ nb1,
    const float* __restrict__ nw2, const float* __restrict__ nb2)
{
    for (int i = threadIdx.x; i < LDS_FLOATS; i += blockDim.x) s[i] = 0.0f;
    __syncthreads();
    for (int t = threadIdx.x; t < 9 * 50; t += blockDim.x) {
        int i = t / 50, j = t - i * 50; s[OFF_EW1 + i * 52 + j] = ew1[t];
    }
    for (int t = threadIdx.x; t < 50 * 15; t += blockDim.x) {
        int j = t / 15, k = t - j * 15; s[OFF_EW2 + j * 16 + k] = ew2[t];
    }
    for (int t = threadIdx.x; t < 18 * 50; t += blockDim.x) {
        int i = t / 50, j = t - i * 50; s[OFF_NW1 + i * 52 + j] = nw1[t];
    }
    for (int t = threadIdx.x; t < 50 * 15; t += blockDim.x) {
        int j = t / 15, k = t - j * 15; s[OFF_NW2 + j * 16 + k] = nw2[t];
    }
    for (int t = threadIdx.x; t < 50; t += blockDim.x) s[OFF_EB1 + t] = eb1[t];
    for (int t = threadIdx.x; t < 15; t += blockDim.x) s[OFF_EB2 + t] = eb2[t];
    for (int t = threadIdx.x; t < 50; t += blockDim.x) s[OFF_NB1 + t] = nb1[t];
    for (int t = threadIdx.x; t < 15; t += blockDim.x) s[OFF_NB2 + t] = nb2[t];
    __syncthreads();
}

__device__ __forceinline__ void mlp_msg(const float* __restrict__ s,
                                        const float ein[9], float m[D3])
{
    float h1[D2];
    #pragma unroll
    for (int j = 0; j < D2; j++) h1[j] = s[OFF_EB1 + j];
    #pragma unroll
    for (int i = 0; i < 9; i++) {
        float v = ein[i];
        #pragma unroll
        for (int j = 0; j < D2; j++) h1[j] = fmaf(v, s[OFF_EW1 + i * 52 + j], h1[j]);
    }
    #pragma unroll
    for (int j = 0; j < D2; j++) h1[j] = fmaxf(h1[j], 0.0f);

    float e2[D3];
    #pragma unroll
    for (int k = 0; k < D3; k++) e2[k] = s[OFF_EB2 + k];
    #pragma unroll
    for (int j = 0; j < D2; j++) {
        float v = h1[j];
        #pragma unroll
        for (int k = 0; k < D3; k++) e2[k] = fmaf(v, s[OFF_EW2 + j * 16 + k], e2[k]);
    }

    float h2[D2];
    #pragma unroll
    for (int j = 0; j < D2; j++) h2[j] = s[OFF_NB1 + j];
    #pragma unroll
    for (int i = 0; i < 3; i++) {
        float v = ein[3 + i];
        #pragma unroll
        for (int j = 0; j < D2; j++) h2[j] = fmaf(v, s[OFF_NW1 + i * 52 + j], h2[j]);
    }
    #pragma unroll
    for (int k = 0; k < D3; k++) {
        float v = e2[k];
        #pragma unroll
        for (int j = 0; j < D2; j++) h2[j] = fmaf(v, s[OFF_NW1 + (3 + k) * 52 + j], h2[j]);
    }
    #pragma unroll
    for (int j = 0; j < D2; j++) h2[j] = fmaxf(h2[j], 0.0f);

    #pragma unroll
    for (int k = 0; k < D3; k++) m[k] = s[OFF_NB2 + k];
    #pragma unroll
    for (int j = 0; j < D2; j++) {
        float v = h2[j];
        #pragma unroll
        for (int k = 0; k < D3; k++) m[k] = fmaf(v, s[OFF_NW2 + j * 16 + k], m[k]);
    }
}

// ---------- full path: edge-parallel MLP -> msg buffer ----------
__global__ __launch_bounds__(256) void edge_kernel(
    const float* __restrict__ x, const float* __restrict__ edge_attr,
    const float* __restrict__ ew1, const float* __restrict__ eb1,
    const float* __restrict__ ew2, const float* __restrict__ eb2,
    const float* __restrict__ nw1, const float* __restrict__ nb1,
    const float* __restrict__ nw2, const float* __restrict__ nb2,
    const int* __restrict__ edge_index,
    float* __restrict__ msg, int* __restrict__ counts)
{
    __shared__ float s[LDS_FLOATS];
    stage_weights(s, ew1, eb1, ew2, eb2, nw1, nb1, nw2, nb2);

    int e = blockIdx.x * 256 + threadIdx.x;
    if (e >= N_EDGES) return;
    int row = edge_index[e];
    int col = edge_index[N_EDGES + e];

    float ein[9];
    ein[0] = x[row * 3 + 0]; ein[1] = x[row * 3 + 1]; ein[2] = x[row * 3 + 2];
    ein[3] = x[col * 3 + 0]; ein[4] = x[col * 3 + 1]; ein[5] = x[col * 3 + 2];
    ein[6] = edge_attr[e * 3 + 0];
    ein[7] = edge_attr[e * 3 + 1];
    ein[8] = edge_attr[e * 3 + 2];

    float m[D3];
    mlp_msg(s, ein, m);

    float4* mp = (float4*)(msg + (size_t)e * 16);
    mp[0] = make_float4(m[0], m[1], m[2], m[3]);
    mp[1] = make_float4(m[4], m[5], m[6], m[7]);
    mp[2] = make_float4(m[8], m[9], m[10], m[11]);
    mp[3] = make_float4(m[12], m[13], m[14], 0.0f);

    atomicAdd(&counts[row], 1);
}

// ---------- compact path: histogram only ----------
__global__ __launch_bounds__(256) void hist_kernel(
    const int* __restrict__ edge_index, int* __restrict__ counts)
{
    int e = blockIdx.x * 256 + threadIdx.x;
    if (e >= N_EDGES) return;
    atomicAdd(&counts[edge_index[e]], 1);
}

// ---------- CSR build: scan + scatter ----------
__global__ __launch_bounds__(1024) void scan1_kernel(
    const int* __restrict__ counts, int* __restrict__ scanned, int* __restrict__ bsums)
{
    __shared__ int tmp[1024];
    int i = blockIdx.x * 1024 + threadIdx.x;
    int v = (i < N_NODES) ? counts[i] : 0;
    tmp[threadIdx.x] = v;
    __syncthreads();
    #pragma unroll
    for (int off = 1; off < 1024; off <<= 1) {
        int t = (threadIdx.x >= off) ? tmp[threadIdx.x - off] : 0;
        __syncthreads();
        tmp[threadIdx.x] += t;
        __syncthreads();
    }
    int incl = tmp[threadIdx.x];
    if (i < N_NODES) scanned[i] = incl - v;
    if (threadIdx.x == 1023) bsums[blockIdx.x] = incl;
}

__global__ __launch_bounds__(128) void scan2_kernel(
    const int* __restrict__ bsums, int* __restrict__ bofs)
{
    __shared__ int tmp[128];
    int v = (threadIdx.x < NBLK1) ? bsums[threadIdx.x] : 0;
    tmp[threadIdx.x] = v;
    __syncthreads();
    #pragma unroll
    for (int off = 1; off < 128; off <<= 1) {
        int t = (threadIdx.x >= off) ? tmp[threadIdx.x - off] : 0;
        __syncthreads();
        tmp[threadIdx.x] += t;
        __syncthreads();
    }
    if (threadIdx.x < NBLK1) bofs[threadIdx.x] = tmp[threadIdx.x] - v;
}

__global__ __launch_bounds__(256) void scan3_kernel(
    const int* __restrict__ scanned, const int* __restrict__ bofs,
    int* __restrict__ cursor)
{
    int n = blockIdx.x * 256 + threadIdx.x;
    if (n >= N_NODES) return;
    cursor[n] = scanned[n] + bofs[n >> 10];
}

__global__ __launch_bounds__(256) void scatter_kernel(
    const int* __restrict__ edge_index, int* __restrict__ cursor,
    int* __restrict__ eids)
{
    int e = blockIdx.x * 256 + threadIdx.x;
    if (e >= N_EDGES) return;
    int row = edge_index[e];
    int pos = atomicAdd(&cursor[row], 1);
    eids[pos] = e;
}

// ---------- gather: sum messages per node ----------
__global__ __launch_bounds__(256) void gather_kernel(
    const float* __restrict__ msg, const int* __restrict__ scanned,
    const int* __restrict__ bofs, const int* __restrict__ counts,
    const int* __restrict__ eids, float* __restrict__ x2)
{
    int n = blockIdx.x * 256 + threadIdx.x;
    if (n >= N_NODES) return;
    int start = scanned[n] + bofs[n >> 10];
    int deg = counts[n];
    float acc[D3];
    #pragma unroll
    for (int k = 0; k < D3; k++) acc[k] = 0.0f;
    for (int j = 0; j < deg; j++) {
        int e = eids[start + j];
        const float4* mp = (const float4*)(msg + (size_t)e * 16);
        float4 a = mp[0], b = mp[1], c = mp[2], d = mp[3];
        acc[0] += a.x;  acc[1] += a.y;  acc[2] += a.z;  acc[3] += a.w;
        acc[4] += b.x;  acc[5] += b.y;  acc[6] += b.z;  acc[7] += b.w;
        acc[8] += c.x;  acc[9] += c.y;  acc[10] += c.z; acc[11] += c.w;
        acc[12] += d.x; acc[13] += d.y; acc[14] += d.z;
    }
    float inv = 1.0f / fmaxf((float)deg, 1.0f);
    float4* xp = (float4*)(x2 + (size_t)n * 16);
    xp[0] = make_float4(acc[0] * inv, acc[1] * inv, acc[2] * inv, acc[3] * inv);
    xp[1] = make_float4(acc[4] * inv, acc[5] * inv, acc[6] * inv, acc[7] * inv);
    xp[2] = make_float4(acc[8] * inv, acc[9] * inv, acc[10] * inv, acc[11] * inv);
    xp[3] = make_float4(acc[12] * inv, acc[13] * inv, acc[14] * inv, 0.0f);
}

// ---------- compact path gather: recompute MLP per edge ----------
__global__ __launch_bounds__(256) void gather_recompute_kernel(
    const float* __restrict__ x, const float* __restrict__ edge_attr,
    const float* __restrict__ ew1, const float* __restrict__ eb1,
    const float* __restrict__ ew2, const float* __restrict__ eb2,
    const float* __restrict__ nw1, const float* __restrict__ nb1,
    const float* __restrict__ nw2, const float* __restrict__ nb2,
    const int* __restrict__ edge_index,
    const int* __restrict__ scanned, const int* __restrict__ bofs,
    const int* __restrict__ counts, const int* __restrict__ eids,
    float* __restrict__ x2)
{
    __shared__ float s[LDS_FLOATS];
    stage_weights(s, ew1, eb1, ew2, eb2, nw1, nb1, nw2, nb2);

    int n = blockIdx.x * 256 + threadIdx.x;
    if (n >= N_NODES) return;
    int start = scanned[n] + bofs[n >> 10];
    int deg = counts[n];
    float xr0 = x[n * 3 + 0], xr1 = x[n * 3 + 1], xr2 = x[n * 3 + 2];
    float acc[D3];
    #pragma unroll
    for (int k = 0; k < D3; k++) acc[k] = 0.0f;
    for (int j = 0; j < deg; j++) {
        int e = eids[start + j];
        int col = edge_index[N_EDGES + e];
        float ein[9];
        ein[0] = xr0; ein[1] = xr1; ein[2] = xr2;
        ein[3] = x[col * 3 + 0]; ein[4] = x[col * 3 + 1]; ein[5] = x[col * 3 + 2];
        ein[6] = edge_attr[e * 3 + 0];
        ein[7] = edge_attr[e * 3 + 1];
        ein[8] = edge_attr[e * 3 + 2];
        float m[D3];
        mlp_msg(s, ein, m);
        #pragma unroll
        for (int k = 0; k < D3; k++) acc[k] += m[k];
    }
    float inv = 1.0f / fmaxf((float)deg, 1.0f);
    float4* xp = (float4*)(x2 + (size_t)n * 16);
    xp[0] = make_float4(acc[0] * inv, acc[1] * inv, acc[2] * inv, acc[3] * inv);
    xp[1] = make_float4(acc[4] * inv, acc[5] * inv, acc[6] * inv, acc[7] * inv);
    xp[2] = make_float4(acc[8] * inv, acc[9] * inv, acc[10] * inv, acc[11] * inv);
    xp[3] = make_float4(acc[12] * inv, acc[13] * inv, acc[14] * inv, 0.0f);
}

// ---------- pool: batch is sorted -> block LDS pre-reduction ----------
__global__ __launch_bounds__(256) void pool_kernel(
    const float* __restrict__ x2, const int* __restrict__ batch,
    float* __restrict__ gsum)
{
    __shared__ float acc[64 * 16];
    int n0 = blockIdx.x * 256;
    int n = n0 + threadIdx.x;
    int gmin = batch[n0];
    int gmax = batch[min(n0 + 255, N_NODES - 1)];
    int range = gmax - gmin + 1;
    if (range <= 64) {
        for (int t = threadIdx.x; t < range * 16; t += 256) acc[t] = 0.0f;
        __syncthreads();
        if (n < N_NODES) {
            int g = batch[n] - gmin;
            const float4* xp = (const float4*)(x2 + (size_t)n * 16);
            float4 a = xp[0], b = xp[1], c = xp[2], d = xp[3];
            float* dst = &acc[g * 16];
            atomicAdd(&dst[0], a.x);  atomicAdd(&dst[1], a.y);
            atomicAdd(&dst[2], a.z);  atomicAdd(&dst[3], a.w);
            atomicAdd(&dst[4], b.x);  atomicAdd(&dst[5], b.y);
            atomicAdd(&dst[6], b.z);  atomicAdd(&dst[7], b.w);
            atomicAdd(&dst[8], c.x);  atomicAdd(&dst[9], c.y);
            atomicAdd(&dst[10], c.z); atomicAdd(&dst[11], c.w);
            atomicAdd(&dst[12], d.x); atomicAdd(&dst[13], d.y);
            atomicAdd(&dst[14], d.z); atomicAdd(&dst[15], 1.0f);
        }
        __syncthreads();
        for (int t = threadIdx.x; t < range * 16; t += 256) {
            float v = acc[t];
            if (v != 0.0f) atomicAdd(&gsum[(size_t)gmin * 16 + t], v);
        }
    } else {
        if (n < N_NODES) {
            int g = batch[n];
            const float4* xp = (const float4*)(x2 + (size_t)n * 16);
            float4 a = xp[0], b = xp[1], c = xp[2], d = xp[3];
            float* dst = gsum + (size_t)g * 16;
            atomicAdd(&dst[0], a.x);  atomicAdd(&dst[1], a.y);
            atomicAdd(&dst[2], a.z);  atomicAdd(&dst[3], a.w);
            atomicAdd(&dst[4], b.x);  atomicAdd(&dst[5], b.y);
            atomicAdd(&dst[6], b.z);  atomicAdd(&dst[7], b.w);
            atomicAdd(&dst[8], c.x);  atomicAdd(&dst[9], c.y);
            atomicAdd(&dst[10], c.z); atomicAdd(&dst[11], c.w);
            atomicAdd(&dst[12], d.x); atomicAdd(&dst[13], d.y);
            atomicAdd(&dst[14], d.z); atomicAdd(&dst[15], 1.0f);
        }
    }
}

// ---------- head ----------
__global__ __launch_bounds__(512) void head_kernel(
    const float* __restrict__ gsum,
    const float* __restrict__ fc1w, const float* __restrict__ fc1b,
    const float* __restrict__ gamma, const float* __restrict__ beta,
    const float* __restrict__ fc2w, const float* __restrict__ fc2b,
    float* __restrict__ out)
{
    __shared__ float ssum[D5], ssq[D5], smu[D5], sistd[D5];
    int g = threadIdx.x;
    if (g < D5) { ssum[g] = 0.0f; ssq[g] = 0.0f; }
    __syncthreads();

    const float* src = gsum + (size_t)g * 16;
    float inv = 1.0f / fmaxf(src[15], 1.0f);
    float u[D3];
    #pragma unroll
    for (int k = 0; k < D3; k++) u[k] = src[k] * inv;

    float h[D5];
    #pragma unroll
    for (int c = 0; c < D5; c++) h[c] = fc1b[c];
    #pragma unroll
    for (int k = 0; k < D3; k++) {
        float v = u[k];
        #pragma unroll
        for (int c = 0; c < D5; c++) h[c] = fmaf(v, fc1w[k * D5 + c], h[c]);
    }

    int lane = threadIdx.x & 63;
    #pragma unroll
    for (int c = 0; c < D5; c++) {
        float v = h[c];
        float v2 = v * v;
        #pragma unroll
        for (int off = 32; off >= 1; off >>= 1) {
            v  += __shfl_xor(v,  off);
            v2 += __shfl_xor(v2, off);
        }
        if (lane == 0) { atomicAdd(&ssum[c], v); atomicAdd(&ssq[c], v2); }
    }
    __syncthreads();
    if (g < D5) {
        float mu = ssum[g] * (1.0f / NUM_GRAPHS);
        float var = ssq[g] * (1.0f / NUM_GRAPHS) - mu * mu;
        smu[g] = mu;
        sistd[g] = rsqrtf(var + BN_EPS);
    }
    __syncthreads();

    float hn[D5];
    #pragma unroll
    for (int c = 0; c < D5; c++) {
        float v = gamma[c] * (h[c] - smu[c]) * sistd[c] + beta[c];
        hn[c] = fmaxf(v, 0.0f);
    }

    float lg[NCLS];
    #pragma unroll
    for (int j = 0; j < NCLS; j++) lg[j] = fc2b[j];
    #pragma unroll
    for (int c = 0; c < D5; c++) {
        float v = hn[c];
        #pragma unroll
        for (int j = 0; j < NCLS; j++) lg[j] = fmaf(v, fc2w[c * NCLS + j], lg[j]);
    }

    float m = lg[0];
    #pragma unroll
    for (int j = 1; j < NCLS; j++) m = fmaxf(m, lg[j]);
    float se = 0.0f;
    #pragma unroll
    for (int j = 0; j < NCLS; j++) se += expf(lg[j] - m);
    float lse = logf(se);
    #pragma unroll
    for (int j = 0; j < NCLS; j++) out[g * NCLS + j] = lg[j] - m - lse;
}

extern "C" void kernel_launch(void* const* d_in, const int* in_sizes, int n_in,
                              void* d_out, int out_size, void* d_ws, size_t ws_size,
                              hipStream_t stream) {
    const float* x         = (const float*)d_in[0];
    const float* edge_attr = (const float*)d_in[1];
    const float* ew1  = (const float*)d_in[2];
    const float* eb1  = (const float*)d_in[3];
    const float* ew2  = (const float*)d_in[4];
    const float* eb2  = (const float*)d_in[5];
    const float* nw1  = (const float*)d_in[6];
    const float* nb1  = (const float*)d_in[7];
    const float* nw2  = (const float*)d_in[8];
    const float* nb2  = (const float*)d_in[9];
    const float* fc1w = (const float*)d_in[10];
    const float* fc1b = (const float*)d_in[11];
    const float* gamma= (const float*)d_in[12];
    const float* beta = (const float*)d_in[13];
    const float* fc2w = (const float*)d_in[14];
    const float* fc2b = (const float*)d_in[15];
    const int* edge_index = (const int*)d_in[16];
    const int* batch      = (const int*)d_in[17];

    // workspace layout
    char* p = (char*)d_ws;
    size_t msg_bytes   = (size_t)N_EDGES * 16 * sizeof(float);   // 102.4 MB
    size_t eids_bytes  = (size_t)N_EDGES * sizeof(int);          // 6.4 MB
    size_t n_bytes     = (size_t)N_NODES * sizeof(int);          // 0.4 MB
    size_t x2_bytes    = (size_t)N_NODES * 16 * sizeof(float);   // 6.4 MB
    size_t gsum_bytes  = (size_t)NUM_GRAPHS * 16 * sizeof(float);
    size_t small_bytes = 128 * sizeof(int);

    size_t need_compact = eids_bytes + 3 * n_bytes + x2_bytes + gsum_bytes + 2 * small_bytes;
    bool full = (ws_size >= need_compact + msg_bytes);

    float* msg = nullptr;
    if (full) { msg = (float*)p; p += msg_bytes; }
    int* eids    = (int*)p; p += eids_bytes;
    int* counts  = (int*)p; p += n_bytes;
    int* scanned = (int*)p; p += n_bytes;
    int* cursor  = (int*)p; p += n_bytes;
    int* bsums   = (int*)p; p += small_bytes;
    int* bofs    = (int*)p; p += small_bytes;
    float* x2    = (float*)p; p += x2_bytes;
    float* gsum  = (float*)p; p += gsum_bytes;

    hipMemsetAsync(counts, 0, n_bytes, stream);
    hipMemsetAsync(gsum, 0, gsum_bytes, stream);

    int egrid = (N_EDGES + 255) / 256;
    int ngrid = (N_NODES + 255) / 256;

    if (full) {
        edge_kernel<<<egrid, 256, 0, stream>>>(
            x, edge_attr, ew1, eb1, ew2, eb2, nw1, nb1, nw2, nb2,
            edge_index, msg, counts);
    } else {
        hist_kernel<<<egrid, 256, 0, stream>>>(edge_index, counts);
    }
    scan1_kernel<<<NBLK1, 1024, 0, stream>>>(counts, scanned, bsums);
    scan2_kernel<<<1, 128, 0, stream>>>(bsums, bofs);
    scan3_kernel<<<ngrid, 256, 0, stream>>>(scanned, bofs, cursor);
    scatter_kernel<<<egrid, 256, 0, stream>>>(edge_index, cursor, eids);
    if (full) {
        gather_kernel<<<ngrid, 256, 0, stream>>>(msg, scanned, bofs, counts, eids, x2);
    } else {
        gather_recompute_kernel<<<ngrid, 256, 0, stream>>>(
            x, edge_attr, ew1, eb1, ew2, eb2, nw1, nb1, nw2, nb2,
            edge_index, scanned, bofs, counts, eids, x2);
    }
    pool_kernel<<<ngrid, 256, 0, stream>>>(x2, batch, gsum);
    head_kernel<<<1, 512, 0, stream>>>(
        gsum, fc1w, fc1b, gamma, beta, fc2w, fc2b, (float*)d_out);
}

// Round 3
// 438.746 us; speedup vs baseline: 3.7450x; 1.3975x over previous
//
#include <hip/hip_runtime.h>
#include <math.h>

#define N_NODES    100000
#define N_EDGES    1600000
#define NUM_GRAPHS 512
#define D1 3
#define D2 50
#define D3 15
#define D5 10
#define NCLS 6
#define BN_EPS 1e-5f

#define NBLK1 ((N_NODES + 1023) / 1024)   // 98 scan blocks

// ---------- pad x to float4 for single-load gathers ----------
__global__ __launch_bounds__(256) void xpad_kernel(
    const float* __restrict__ x, float4* __restrict__ x4)
{
    int n = blockIdx.x * 256 + threadIdx.x;
    if (n >= N_NODES) return;
    x4[n] = make_float4(x[n * 3 + 0], x[n * 3 + 1], x[n * 3 + 2], 0.0f);
}

// ---------- in-degree histogram ----------
__global__ __launch_bounds__(256) void hist_kernel(
    const int* __restrict__ edge_index, int* __restrict__ counts)
{
    int e = blockIdx.x * 256 + threadIdx.x;
    if (e >= N_EDGES) return;
    atomicAdd(&counts[edge_index[e]], 1);
}

// ---------- CSR offsets: block scan + block-sum scan + add ----------
__global__ __launch_bounds__(1024) void scan1_kernel(
    const int* __restrict__ counts, int* __restrict__ scanned, int* __restrict__ bsums)
{
    __shared__ int tmp[1024];
    int i = blockIdx.x * 1024 + threadIdx.x;
    int v = (i < N_NODES) ? counts[i] : 0;
    tmp[threadIdx.x] = v;
    __syncthreads();
    #pragma unroll
    for (int off = 1; off < 1024; off <<= 1) {
        int t = (threadIdx.x >= off) ? tmp[threadIdx.x - off] : 0;
        __syncthreads();
        tmp[threadIdx.x] += t;
        __syncthreads();
    }
    int incl = tmp[threadIdx.x];
    if (i < N_NODES) scanned[i] = incl - v;
    if (threadIdx.x == 1023) bsums[blockIdx.x] = incl;
}

__global__ __launch_bounds__(128) void scan2_kernel(
    const int* __restrict__ bsums, int* __restrict__ bofs)
{
    __shared__ int tmp[128];
    int v = (threadIdx.x < NBLK1) ? bsums[threadIdx.x] : 0;
    tmp[threadIdx.x] = v;
    __syncthreads();
    #pragma unroll
    for (int off = 1; off < 128; off <<= 1) {
        int t = (threadIdx.x >= off) ? tmp[threadIdx.x - off] : 0;
        __syncthreads();
        tmp[threadIdx.x] += t;
        __syncthreads();
    }
    if (threadIdx.x < NBLK1) bofs[threadIdx.x] = tmp[threadIdx.x] - v;
}

__global__ __launch_bounds__(256) void scan3_kernel(
    const int* __restrict__ scanned, const int* __restrict__ bofs,
    int* __restrict__ cursor)
{
    int n = blockIdx.x * 256 + threadIdx.x;
    if (n >= N_NODES) return;
    cursor[n] = scanned[n] + bofs[n >> 10];
}

// ---------- fused MLPs; weights read via scalar (uniform) loads ----------
__global__ __launch_bounds__(256) void edge_kernel(
    const float4* __restrict__ x4, const float* __restrict__ edge_attr,
    const float* __restrict__ ew1, const float* __restrict__ eb1,
    const float* __restrict__ ew2, const float* __restrict__ eb2,
    const float* __restrict__ nw1, const float* __restrict__ nb1,
    const float* __restrict__ nw2, const float* __restrict__ nb2,
    const int* __restrict__ edge_index,
    int* __restrict__ cursor, float* __restrict__ msg)
{
    int e = blockIdx.x * 256 + threadIdx.x;
    if (e >= N_EDGES) return;
    int row = edge_index[e];
    int col = edge_index[N_EDGES + e];

    float4 xr = x4[row];
    float4 xc = x4[col];
    float ein[9];
    ein[0] = xr.x; ein[1] = xr.y; ein[2] = xr.z;
    ein[3] = xc.x; ein[4] = xc.y; ein[5] = xc.z;
    ein[6] = edge_attr[e * 3 + 0];
    ein[7] = edge_attr[e * 3 + 1];
    ein[8] = edge_attr[e * 3 + 2];

    // edge MLP layer 1: [9] -> [50], relu   (weights uniform -> SGPR)
    float h1[D2];
    #pragma unroll
    for (int j = 0; j < D2; j++) h1[j] = eb1[j];
    #pragma unroll
    for (int i = 0; i < 9; i++) {
        float v = ein[i];
        #pragma unroll
        for (int j = 0; j < D2; j++) h1[j] = fmaf(v, ew1[i * 50 + j], h1[j]);
    }
    #pragma unroll
    for (int j = 0; j < D2; j++) h1[j] = fmaxf(h1[j], 0.0f);

    // edge MLP layer 2: [50] -> [15]
    float e2[D3];
    #pragma unroll
    for (int k = 0; k < D3; k++) e2[k] = eb2[k];
    #pragma unroll
    for (int j = 0; j < D2; j++) {
        float v = h1[j];
        #pragma unroll
        for (int k = 0; k < D3; k++) e2[k] = fmaf(v, ew2[j * 15 + k], e2[k]);
    }

    // node MLP layer 1: [x[col](3), e2(15)] -> [50], relu
    float h2[D2];
    #pragma unroll
    for (int j = 0; j < D2; j++) h2[j] = nb1[j];
    #pragma unroll
    for (int i = 0; i < 3; i++) {
        float v = ein[3 + i];
        #pragma unroll
        for (int j = 0; j < D2; j++) h2[j] = fmaf(v, nw1[i * 50 + j], h2[j]);
    }
    #pragma unroll
    for (int k = 0; k < D3; k++) {
        float v = e2[k];
        #pragma unroll
        for (int j = 0; j < D2; j++) h2[j] = fmaf(v, nw1[(3 + k) * 50 + j], h2[j]);
    }
    #pragma unroll
    for (int j = 0; j < D2; j++) h2[j] = fmaxf(h2[j], 0.0f);

    // node MLP layer 2: [50] -> [15]
    float m[D3];
    #pragma unroll
    for (int k = 0; k < D3; k++) m[k] = nb2[k];
    #pragma unroll
    for (int j = 0; j < D2; j++) {
        float v = h2[j];
        #pragma unroll
        for (int k = 0; k < D3; k++) m[k] = fmaf(v, nw2[j * 15 + k], m[k]);
    }

    // write message into its CSR slot (scattered full-line store)
    int pos = atomicAdd(&cursor[row], 1);
    float4* mp = (float4*)(msg + (size_t)pos * 16);
    mp[0] = make_float4(m[0], m[1], m[2], m[3]);
    mp[1] = make_float4(m[4], m[5], m[6], m[7]);
    mp[2] = make_float4(m[8], m[9], m[10], m[11]);
    mp[3] = make_float4(m[12], m[13], m[14], 0.0f);
}

// ---------- gather: sequential CSR segment sum ----------
__global__ __launch_bounds__(256) void gather_kernel(
    const float* __restrict__ msg, const int* __restrict__ scanned,
    const int* __restrict__ bofs, const int* __restrict__ counts,
    float* __restrict__ x2)
{
    int n = blockIdx.x * 256 + threadIdx.x;
    if (n >= N_NODES) return;
    int start = scanned[n] + bofs[n >> 10];
    int deg = counts[n];
    float4 a0 = make_float4(0.f, 0.f, 0.f, 0.f);
    float4 a1 = a0, a2 = a0, a3 = a0;
    for (int j = 0; j < deg; j++) {
        const float4* mp = (const float4*)(msg + (size_t)(start + j) * 16);
        float4 b0 = mp[0], b1 = mp[1], b2 = mp[2], b3 = mp[3];
        a0.x += b0.x; a0.y += b0.y; a0.z += b0.z; a0.w += b0.w;
        a1.x += b1.x; a1.y += b1.y; a1.z += b1.z; a1.w += b1.w;
        a2.x += b2.x; a2.y += b2.y; a2.z += b2.z; a2.w += b2.w;
        a3.x += b3.x; a3.y += b3.y; a3.z += b3.z;
    }
    float inv = 1.0f / fmaxf((float)deg, 1.0f);
    float4* xp = (float4*)(x2 + (size_t)n * 16);
    xp[0] = make_float4(a0.x * inv, a0.y * inv, a0.z * inv, a0.w * inv);
    xp[1] = make_float4(a1.x * inv, a1.y * inv, a1.z * inv, a1.w * inv);
    xp[2] = make_float4(a2.x * inv, a2.y * inv, a2.z * inv, a2.w * inv);
    xp[3] = make_float4(a3.x * inv, a3.y * inv, a3.z * inv, 0.0f);
}

// ---------- pool: batch sorted -> block LDS pre-reduction ----------
__global__ __launch_bounds__(256) void pool_kernel(
    const float* __restrict__ x2, const int* __restrict__ batch,
    float* __restrict__ gsum)
{
    __shared__ float acc[64 * 16];
    int n0 = blockIdx.x * 256;
    int n = n0 + threadIdx.x;
    int gmin = batch[n0];
    int gmax = batch[min(n0 + 255, N_NODES - 1)];
    int range = gmax - gmin + 1;
    if (range <= 64) {
        for (int t = threadIdx.x; t < range * 16; t += 256) acc[t] = 0.0f;
        __syncthreads();
        if (n < N_NODES) {
            int g = batch[n] - gmin;
            const float4* xp = (const float4*)(x2 + (size_t)n * 16);
            float4 a = xp[0], b = xp[1], c = xp[2], d = xp[3];
            float* dst = &acc[g * 16];
            atomicAdd(&dst[0], a.x);  atomicAdd(&dst[1], a.y);
            atomicAdd(&dst[2], a.z);  atomicAdd(&dst[3], a.w);
            atomicAdd(&dst[4], b.x);  atomicAdd(&dst[5], b.y);
            atomicAdd(&dst[6], b.z);  atomicAdd(&dst[7], b.w);
            atomicAdd(&dst[8], c.x);  atomicAdd(&dst[9], c.y);
            atomicAdd(&dst[10], c.z); atomicAdd(&dst[11], c.w);
            atomicAdd(&dst[12], d.x); atomicAdd(&dst[13], d.y);
            atomicAdd(&dst[14], d.z); atomicAdd(&dst[15], 1.0f);
        }
        __syncthreads();
        for (int t = threadIdx.x; t < range * 16; t += 256) {
            float v = acc[t];
            if (v != 0.0f) atomicAdd(&gsum[(size_t)gmin * 16 + t], v);
        }
    } else {
        if (n < N_NODES) {
            int g = batch[n];
            const float4* xp = (const float4*)(x2 + (size_t)n * 16);
            float4 a = xp[0], b = xp[1], c = xp[2], d = xp[3];
            float* dst = gsum + (size_t)g * 16;
            atomicAdd(&dst[0], a.x);  atomicAdd(&dst[1], a.y);
            atomicAdd(&dst[2], a.z);  atomicAdd(&dst[3], a.w);
            atomicAdd(&dst[4], b.x);  atomicAdd(&dst[5], b.y);
            atomicAdd(&dst[6], b.z);  atomicAdd(&dst[7], b.w);
            atomicAdd(&dst[8], c.x);  atomicAdd(&dst[9], c.y);
            atomicAdd(&dst[10], c.z); atomicAdd(&dst[11], c.w);
            atomicAdd(&dst[12], d.x); atomicAdd(&dst[13], d.y);
            atomicAdd(&dst[14], d.z); atomicAdd(&dst[15], 1.0f);
        }
    }
}

// ---------- head ----------
__global__ __launch_bounds__(512) void head_kernel(
    const float* __restrict__ gsum,
    const float* __restrict__ fc1w, const float* __restrict__ fc1b,
    const float* __restrict__ gamma, const float* __restrict__ beta,
    const float* __restrict__ fc2w, const float* __restrict__ fc2b,
    float* __restrict__ out)
{
    __shared__ float ssum[D5], ssq[D5], smu[D5], sistd[D5];
    int g = threadIdx.x;
    if (g < D5) { ssum[g] = 0.0f; ssq[g] = 0.0f; }
    __syncthreads();

    const float* src = gsum + (size_t)g * 16;
    float inv = 1.0f / fmaxf(src[15], 1.0f);
    float u[D3];
    #pragma unroll
    for (int k = 0; k < D3; k++) u[k] = src[k] * inv;

    float h[D5];
    #pragma unroll
    for (int c = 0; c < D5; c++) h[c] = fc1b[c];
    #pragma unroll
    for (int k = 0; k < D3; k++) {
        float v = u[k];
        #pragma unroll
        for (int c = 0; c < D5; c++) h[c] = fmaf(v, fc1w[k * D5 + c], h[c]);
    }

    int lane = threadIdx.x & 63;
    #pragma unroll
    for (int c = 0; c < D5; c++) {
        float v = h[c];
        float v2 = v * v;
        #pragma unroll
        for (int off = 32; off >= 1; off >>= 1) {
            v  += __shfl_xor(v,  off);
            v2 += __shfl_xor(v2, off);
        }
        if (lane == 0) { atomicAdd(&ssum[c], v); atomicAdd(&ssq[c], v2); }
    }
    __syncthreads();
    if (g < D5) {
        float mu = ssum[g] * (1.0f / NUM_GRAPHS);
        float var = ssq[g] * (1.0f / NUM_GRAPHS) - mu * mu;
        smu[g] = mu;
        sistd[g] = rsqrtf(var + BN_EPS);
    }
    __syncthreads();

    float hn[D5];
    #pragma unroll
    for (int c = 0; c < D5; c++) {
        float v = gamma[c] * (h[c] - smu[c]) * sistd[c] + beta[c];
        hn[c] = fmaxf(v, 0.0f);
    }

    float lg[NCLS];
    #pragma unroll
    for (int j = 0; j < NCLS; j++) lg[j] = fc2b[j];
    #pragma unroll
    for (int c = 0; c < D5; c++) {
        float v = hn[c];
        #pragma unroll
        for (int j = 0; j < NCLS; j++) lg[j] = fmaf(v, fc2w[c * NCLS + j], lg[j]);
    }

    float m = lg[0];
    #pragma unroll
    for (int j = 1; j < NCLS; j++) m = fmaxf(m, lg[j]);
    float se = 0.0f;
    #pragma unroll
    for (int j = 0; j < NCLS; j++) se += expf(lg[j] - m);
    float lse = logf(se);
    #pragma unroll
    for (int j = 0; j < NCLS; j++) out[g * NCLS + j] = lg[j] - m - lse;
}

extern "C" void kernel_launch(void* const* d_in, const int* in_sizes, int n_in,
                              void* d_out, int out_size, void* d_ws, size_t ws_size,
                              hipStream_t stream) {
    const float* x         = (const float*)d_in[0];
    const float* edge_attr = (const float*)d_in[1];
    const float* ew1  = (const float*)d_in[2];
    const float* eb1  = (const float*)d_in[3];
    const float* ew2  = (const float*)d_in[4];
    const float* eb2  = (const float*)d_in[5];
    const float* nw1  = (const float*)d_in[6];
    const float* nb1  = (const float*)d_in[7];
    const float* nw2  = (const float*)d_in[8];
    const float* nb2  = (const float*)d_in[9];
    const float* fc1w = (const float*)d_in[10];
    const float* fc1b = (const float*)d_in[11];
    const float* gamma= (const float*)d_in[12];
    const float* beta = (const float*)d_in[13];
    const float* fc2w = (const float*)d_in[14];
    const float* fc2b = (const float*)d_in[15];
    const int* edge_index = (const int*)d_in[16];
    const int* batch      = (const int*)d_in[17];

    // workspace layout
    char* p = (char*)d_ws;
    float* msg = (float*)p;        p += (size_t)N_EDGES * 16 * sizeof(float);  // 102.4 MB
    int* counts  = (int*)p;        p += (size_t)N_NODES * sizeof(int);
    int* scanned = (int*)p;        p += (size_t)N_NODES * sizeof(int);
    int* cursor  = (int*)p;        p += (size_t)N_NODES * sizeof(int);
    int* bsums   = (int*)p;        p += 128 * sizeof(int);
    int* bofs    = (int*)p;        p += 128 * sizeof(int);
    float4* x4   = (float4*)p;     p += (size_t)N_NODES * sizeof(float4);
    float* x2    = (float*)p;      p += (size_t)N_NODES * 16 * sizeof(float);
    float* gsum  = (float*)p;      p += (size_t)NUM_GRAPHS * 16 * sizeof(float);

    hipMemsetAsync(counts, 0, (size_t)N_NODES * sizeof(int), stream);
    hipMemsetAsync(gsum, 0, (size_t)NUM_GRAPHS * 16 * sizeof(float), stream);

    int egrid = (N_EDGES + 255) / 256;
    int ngrid = (N_NODES + 255) / 256;

    xpad_kernel<<<ngrid, 256, 0, stream>>>(x, x4);
    hist_kernel<<<egrid, 256, 0, stream>>>(edge_index, counts);
    scan1_kernel<<<NBLK1, 1024, 0, stream>>>(counts, scanned, bsums);
    scan2_kernel<<<1, 128, 0, stream>>>(bsums, bofs);
    scan3_kernel<<<ngrid, 256, 0, stream>>>(scanned, bofs, cursor);
    edge_kernel<<<egrid, 256, 0, stream>>>(
        x4, edge_attr, ew1, eb1, ew2, eb2, nw1, nb1, nw2, nb2,
        edge_index, cursor, msg);
    gather_kernel<<<ngrid, 256, 0, stream>>>(msg, scanned, bofs, counts, x2);
    pool_kernel<<<ngrid, 256, 0, stream>>>(x2, batch, gsum);
    head_kernel<<<1, 512, 0, stream>>>(
        gsum, fc1w, fc1b, gamma, beta, fc2w, fc2b, (float*)d_out);
}